// Round 6
// baseline (301.561 us; speedup 1.0000x reference)
//
#include <hip/hip_runtime.h>
#include <stdint.h>

// ---------- helpers ----------
typedef __attribute__((ext_vector_type(8))) short bf16x8;   // 8 bf16 in 4 VGPRs
typedef __attribute__((ext_vector_type(4))) float f32x4;

__device__ __forceinline__ float bflo(uint32_t v) { return __uint_as_float(v << 16); }
__device__ __forceinline__ float bfhi(uint32_t v) { return __uint_as_float(v & 0xffff0000u); }
__device__ __forceinline__ uint16_t f2bf(float f) {  // RNE, finite inputs only
  uint32_t u = __float_as_uint(f);
  u += 0x7fffu + ((u >> 16) & 1u);
  return (uint16_t)(u >> 16);
}

#define NSHADOW 64   // BN-stats shadow copies (contention / 64)

// ---------- prep: weights f32 -> bf16 Wt[128][K]; features f32 -> bf16;
// biases/gamma/beta -> f32; zero shadow. Grid: 3125 blocks x 256.
__global__ __launch_bounds__(256) void prep_k(
    const float* __restrict__ X,
    const float* __restrict__ W1, const float* __restrict__ Wf1,
    const float* __restrict__ W2, const float* __restrict__ Wf2,
    const float* __restrict__ b1, const float* __restrict__ bf1,
    const float* __restrict__ b2, const float* __restrict__ bf2,
    const float* __restrict__ gam, const float* __restrict__ bet,
    uint16_t* __restrict__ Xb,
    uint16_t* __restrict__ T1, uint16_t* __restrict__ Tf1,
    uint16_t* __restrict__ T2, uint16_t* __restrict__ Tf2,
    float* __restrict__ fb, float* __restrict__ fgb,
    float* __restrict__ shadow, int NF)
{
  int t = blockIdx.x * 256 + threadIdx.x;
  if (t < NSHADOW * 256) shadow[t] = 0.f;
  if (t < 98304) {                          // weight transpose (bf16)
    const float* S; uint16_t* D; int Kw; int e;
    if (t < 16384)      { S = W1;  D = T1;  Kw = 128; e = t; }
    else if (t < 49152) { S = Wf1; D = Tf1; Kw = 256; e = t - 16384; }
    else if (t < 65536) { S = W2;  D = T2;  Kw = 128; e = t - 49152; }
    else                { S = Wf2; D = Tf2; Kw = 256; e = t - 65536; }
    int k = e >> 7, n = e & 127;
    D[n * Kw + k] = f2bf(S[e]);
  }
  {                                         // features -> bf16, 8 elems/thread
    int base = t * 8;
    if (base < NF) {
      f32x4 f0 = *(const f32x4*)(X + base);
      f32x4 f1 = *(const f32x4*)(X + base + 4);
      bf16x8 a;
      a[0] = (short)f2bf(f0[0]); a[1] = (short)f2bf(f0[1]);
      a[2] = (short)f2bf(f0[2]); a[3] = (short)f2bf(f0[3]);
      a[4] = (short)f2bf(f1[0]); a[5] = (short)f2bf(f1[1]);
      a[6] = (short)f2bf(f1[2]); a[7] = (short)f2bf(f1[3]);
      *(bf16x8*)(Xb + base) = a;
    }
  }
  if (blockIdx.x == 0) {
    int i = threadIdx.x;
    for (int j = i; j < 512; j += 256) {    // fb: [b1|bf1|b2|bf2]
      const float* src = (j < 128) ? b1 : (j < 256) ? bf1 : (j < 384) ? b2 : bf2;
      fb[j] = src[j & 127];
    }
    fgb[i] = (i < 128) ? gam[i] : bet[i & 127];   // [gamma|beta]
  }
}

// ---------- LDS-free GEMM: D[M,128] = act(A[M,K] @ W[K,128] + b) ----------
// Wave = 16 rows x 128 cols. A0/A1 bf16 [M][128] (A1 = upper K half when
// K==256). Wt bf16 [128][K] row-major: B-fragment layout == A-fragment
// layout on Wt rows, loaded straight from global (L1/L2-resident, 32-64 KB).
// No LDS, no barriers -> compiler pipelines the whole stream.
template<int K, bool RELU, bool STATS, int ODT>
__global__ __launch_bounds__(256) void gemm_nl(
    const uint16_t* __restrict__ A0, const uint16_t* __restrict__ A1,
    const uint16_t* __restrict__ Wt, const float* __restrict__ bias,
    void* __restrict__ Dv, float* __restrict__ shadow, int M)
{
  constexpr int KT = K / 32;
  const int lane = threadIdx.x & 63;
  const int gw   = blockIdx.x * 4 + (threadIdx.x >> 6);
  const int row0 = gw * 16;
  if (row0 >= M) return;                    // M % 16 == 0
  const int m = lane & 15, quad = lane >> 4;
  const int arow = row0 + m;

  bf16x8 afr[KT];
#pragma unroll
  for (int kk = 0; kk < KT; kk++) {
    const uint16_t* src = (K == 256 && kk >= 4)
        ? (A1 + (size_t)arow * 128 + (kk - 4) * 32)
        : (A0 + (size_t)arow * 128 + kk * 32);
    afr[kk] = *(const bf16x8*)(src + quad * 8);
  }

  const uint16_t* wbase = Wt + (size_t)m * K + quad * 8;
#pragma unroll
  for (int nt = 0; nt < 8; nt++) {
    bf16x8 bfr[KT];
#pragma unroll
    for (int kk = 0; kk < KT; kk++)
      bfr[kk] = *(const bf16x8*)(wbase + (size_t)nt * 16 * K + kk * 32);
    f32x4 acc = {0.f, 0.f, 0.f, 0.f};
#pragma unroll
    for (int kk = 0; kk < KT; kk++)
      acc = __builtin_amdgcn_mfma_f32_16x16x32_bf16(afr[kk], bfr[kk], acc, 0, 0, 0);

    const int col = nt * 16 + m;
    const float bv = bias[col];
    float vals[4];
#pragma unroll
    for (int r = 0; r < 4; r++) {
      float v = acc[r] + bv;
      if (RELU) v = fmaxf(v, 0.f);
      vals[r] = v;
      size_t oidx = (size_t)(row0 + quad * 4 + r) * 128 + col;
      if (ODT == 0) ((uint16_t*)Dv)[oidx] = f2bf(v);
      else          ((float*)Dv)[oidx] = v;
    }
    if (STATS) {
      float s = vals[0] + vals[1] + vals[2] + vals[3];
      float q = vals[0]*vals[0] + vals[1]*vals[1] + vals[2]*vals[2] + vals[3]*vals[3];
      s += __shfl_xor(s, 16); s += __shfl_xor(s, 32);
      q += __shfl_xor(q, 16); q += __shfl_xor(q, 32);
      if (quad == 0) {
        float* slot = shadow + (size_t)(gw & (NSHADOW - 1)) * 256;
        atomicAdd(&slot[col], s);
        atomicAdd(&slot[128 + col], q);
      }
    }
  }
}

// ---------- gather + max over S neighbors (bf16 rows, 4 rows/wave) ----------
template<int S>
__global__ __launch_bounds__(256) void gather_k(
    const uint32_t* __restrict__ H, const int* __restrict__ idx,
    uint32_t* __restrict__ OUT, int M)
{
  const int lane = threadIdx.x & 63;
  const int gw = blockIdx.x * 4 + (threadIdx.x >> 6);
  const int base = gw * 4;
#pragma unroll
  for (int p = 0; p < 2; p++) {             // 2 iterations x 2 interleaved rows
    int ra = base + p * 2, rb = ra + 1;
    if (ra >= M) return;
    bool hb = rb < M;
    const int* ia = idx + (size_t)ra * S;
    const int* ib = idx + (size_t)(hb ? rb : ra) * S;
    float a0 = -3.4e38f, a1 = -3.4e38f, b0 = -3.4e38f, b1 = -3.4e38f;
#pragma unroll
    for (int s = 0; s < S; s++) {
      uint32_t ja = (uint32_t)ia[s]; if (ja >= (uint32_t)M) ja = 0;
      uint32_t jb = (uint32_t)ib[s]; if (jb >= (uint32_t)M) jb = 0;
      uint32_t va = H[(size_t)ja * 64 + lane];
      uint32_t vb = H[(size_t)jb * 64 + lane];
      a0 = fmaxf(a0, bflo(va)); a1 = fmaxf(a1, bfhi(va));
      b0 = fmaxf(b0, bflo(vb)); b1 = fmaxf(b1, bfhi(vb));
    }
    OUT[(size_t)ra * 64 + lane] = (__float_as_uint(a1) & 0xffff0000u) | (__float_as_uint(a0) >> 16);
    if (hb)
      OUT[(size_t)rb * 64 + lane] = (__float_as_uint(b1) & 0xffff0000u) | (__float_as_uint(b0) >> 16);
  }
}

// ---------- BN (batch stats from shadow slots) + row L2 normalize ----------
__global__ __launch_bounds__(256) void bn_norm_k(
    const uint32_t* __restrict__ Y, const float* __restrict__ shadow,
    const float* __restrict__ fgb, uint32_t* __restrict__ X, int M)
{
  __shared__ float sc[128], sh[128];
  const int tid = threadIdx.x;
  if (tid < 128) {
    float s = 0.f, q = 0.f;
    for (int sl = 0; sl < NSHADOW; sl++) {
      s += shadow[sl * 256 + tid];
      q += shadow[sl * 256 + 128 + tid];
    }
    float invN = 1.0f / (float)M;
    float mean = s * invN;
    float var  = fmaxf(q * invN - mean * mean, 0.f);
    float g = fgb[tid] * rsqrtf(var + 1e-5f);
    sc[tid] = g;
    sh[tid] = fgb[128 + tid] - mean * g;
  }
  __syncthreads();
  const int lane = tid & 63;
  const float s0 = sc[2*lane], s1 = sc[2*lane+1];
  const float h0 = sh[2*lane], h1 = sh[2*lane+1];
  int w = blockIdx.x * 4 + (tid >> 6);
  const int nw = gridDim.x * 4;
  for (int r = w; r < M; r += nw) {
    uint32_t v = Y[(size_t)r * 64 + lane];
    float x0 = bflo(v) * s0 + h0;
    float x1 = bfhi(v) * s1 + h1;
    float q = x0*x0 + x1*x1;
    q += __shfl_xor(q, 1);  q += __shfl_xor(q, 2);  q += __shfl_xor(q, 4);
    q += __shfl_xor(q, 8);  q += __shfl_xor(q, 16); q += __shfl_xor(q, 32);
    float inv = 1.0f / (sqrtf(q) + 1e-6f);
    x0 *= inv; x1 *= inv;
    X[(size_t)r * 64 + lane] = ((uint32_t)f2bf(x1) << 16) | (uint32_t)f2bf(x0);
  }
}

// ---------- launch ----------
extern "C" void kernel_launch(void* const* d_in, const int* in_sizes, int n_in,
                              void* d_out, int out_size, void* d_ws, size_t ws_size,
                              hipStream_t stream)
{
  const float* features = (const float*)d_in[0];
  const int*   idx1     = (const int*)d_in[1];
  const int*   idx2     = (const int*)d_in[2];
  const float* agg1_W   = (const float*)d_in[3];
  const float* agg1_b   = (const float*)d_in[4];
  const float* fc1_W    = (const float*)d_in[5];
  const float* fc1_b    = (const float*)d_in[6];
  const float* agg2_W   = (const float*)d_in[7];
  const float* agg2_b   = (const float*)d_in[8];
  const float* fc2_W    = (const float*)d_in[9];
  const float* fc2_b    = (const float*)d_in[10];
  const float* bn_g     = (const float*)d_in[11];
  const float* bn_b     = (const float*)d_in[12];

  const int N  = in_sizes[0] / 128;         // 50000 (multiple of 16)
  const int NF = N * 128;

  // workspace carve-up (16B-aligned); ~39 MB
  char* w = (char*)d_ws;
  float* shadow = (float*)w; w += NSHADOW * 256 * 4;
  uint16_t* T1  = (uint16_t*)w; w += 128 * 128 * 2;
  uint16_t* Tf1 = (uint16_t*)w; w += 128 * 256 * 2;
  uint16_t* T2  = (uint16_t*)w; w += 128 * 128 * 2;
  uint16_t* Tf2 = (uint16_t*)w; w += 128 * 256 * 2;
  float* fb  = (float*)w; w += 512 * 4;     // [b1|bf1|b2|bf2] f32
  float* fgb = (float*)w; w += 256 * 4;     // [gamma|beta] f32
  size_t NB = (size_t)N * 128 * 2;
  uint16_t* Xb   = (uint16_t*)w; w += NB;   // features as bf16
  uint16_t* bufA = (uint16_t*)w; w += NB;   // agg1 -> x
  uint16_t* bufB = (uint16_t*)w; w += NB;   // y -> agg2
  uint16_t* hbuf = (uint16_t*)d_out;        // h1/h2 scratch in d_out (25.6 MB)

  const int pb = (NF / 8 + 255) / 256;      // 3125
  const int gb = ((N + 15) / 16 + 3) / 4;   // 782 (16 rows/wave, 4 waves/blk)
  const int hb = (N + 15) / 16;             // 3125 (4 rows/wave * 4 waves = 16 rows/blk)

  prep_k<<<pb, 256, 0, stream>>>(features, agg1_W, fc1_W, agg2_W, fc2_W,
      agg1_b, fc1_b, agg2_b, fc2_b, bn_g, bn_b,
      Xb, T1, Tf1, T2, Tf2, fb, fgb, shadow, NF);

  // h1 = relu(Xb @ W1 + b1) -> d_out scratch (bf16)
  gemm_nl<128, true, false, 0><<<gb, 256, 0, stream>>>(
      Xb, nullptr, T1, fb + 0, hbuf, nullptr, N);
  // agg1 = max-gather(h1, idx1) -> bufA
  gather_k<25><<<hb, 256, 0, stream>>>((const uint32_t*)hbuf, idx1, (uint32_t*)bufA, N);
  // y = relu([Xb, agg1] @ fc1 + b) -> bufB, fused BN stats
  gemm_nl<256, true, true, 0><<<gb, 256, 0, stream>>>(
      Xb, bufA, Tf1, fb + 128, bufB, shadow, N);
  // x = L2normalize(BN(y)) -> bufA
  bn_norm_k<<<512, 256, 0, stream>>>((const uint32_t*)bufB, shadow, fgb,
                                     (uint32_t*)bufA, N);
  // h2 = relu(x @ W2 + b2) -> d_out scratch
  gemm_nl<128, true, false, 0><<<gb, 256, 0, stream>>>(
      bufA, nullptr, T2, fb + 256, hbuf, nullptr, N);
  // agg2 = max-gather(h2, idx2) -> bufB
  gather_k<25><<<hb, 256, 0, stream>>>((const uint32_t*)hbuf, idx2, (uint32_t*)bufB, N);
  // out = [x, agg2] @ fc2 + b -> d_out (f32)
  gemm_nl<256, false, false, 1><<<gb, 256, 0, stream>>>(
      bufA, bufB, Tf2, fb + 384, d_out, nullptr, N);

  (void)n_in; (void)out_size; (void)ws_size;
}

// Round 7
// 254.636 us; speedup vs baseline: 1.1843x; 1.1843x over previous
//
#include <hip/hip_runtime.h>
#include <stdint.h>

// ---------- helpers ----------
typedef __attribute__((ext_vector_type(8))) short bf16x8;   // 8 bf16 in 4 VGPRs
typedef __attribute__((ext_vector_type(4))) float f32x4;

__device__ __forceinline__ float bflo(uint32_t v) { return __uint_as_float(v << 16); }
__device__ __forceinline__ float bfhi(uint32_t v) { return __uint_as_float(v & 0xffff0000u); }
__device__ __forceinline__ uint16_t f2bf(float f) {  // RNE, finite inputs only
  uint32_t u = __float_as_uint(f);
  u += 0x7fffu + ((u >> 16) & 1u);
  return (uint16_t)(u >> 16);
}

#define NSHADOW 64   // BN-stats shadow copies

// ---------- prep ----------
// Weights f32 [K][128] -> bf16 fragment-order Wf: chunk c=(tile tt, kstep kk),
// lane l=(quad q, m): 8 elems W[kk*32+q*8+j][tt*16+m], stored contiguous at
// Wf + (c*64+l)*8  -> gemm B-loads are lane-sequential fully-coalesced 1KB.
// Also: features f32 -> bf16, biases/gamma/beta -> f32, zero shadow.
__global__ __launch_bounds__(256) void prep_k(
    const float* __restrict__ X,
    const float* __restrict__ W1, const float* __restrict__ Wf1,
    const float* __restrict__ W2, const float* __restrict__ Wf2,
    const float* __restrict__ b1, const float* __restrict__ bf1,
    const float* __restrict__ b2, const float* __restrict__ bf2,
    const float* __restrict__ gam, const float* __restrict__ bet,
    uint16_t* __restrict__ Xb,
    uint16_t* __restrict__ F1, uint16_t* __restrict__ Ff1,
    uint16_t* __restrict__ F2, uint16_t* __restrict__ Ff2,
    float* __restrict__ fb, float* __restrict__ fgb,
    float* __restrict__ shadow, int NF)
{
  int t = blockIdx.x * 256 + threadIdx.x;
  if (t < NSHADOW * 256) shadow[t] = 0.f;
  if (t < 12288) {                          // weight -> fragment order, 8 elems/thread
    const float* W; uint16_t* D; int KTl; int g;
    if (t < 2048)      { W = W1;  D = F1;  KTl = 4; g = t; }
    else if (t < 6144) { W = Wf1; D = Ff1; KTl = 8; g = t - 2048; }
    else if (t < 8192) { W = W2;  D = F2;  KTl = 4; g = t - 6144; }
    else               { W = Wf2; D = Ff2; KTl = 8; g = t - 8192; }
    int c = g >> 6, l = g & 63;
    int tt = c / KTl, kk = c - tt * KTl;
    int m = l & 15, q = l >> 4;
    int n  = tt * 16 + m;
    int k0 = kk * 32 + q * 8;
    bf16x8 a;
#pragma unroll
    for (int j = 0; j < 8; j++) a[j] = (short)f2bf(W[(size_t)(k0 + j) * 128 + n]);
    *(bf16x8*)(D + (size_t)g * 8) = a;
  }
  {                                         // features -> bf16, 8 elems/thread
    int base = t * 8;
    if (base < NF) {
      f32x4 f0 = *(const f32x4*)(X + base);
      f32x4 f1 = *(const f32x4*)(X + base + 4);
      bf16x8 a;
      a[0] = (short)f2bf(f0[0]); a[1] = (short)f2bf(f0[1]);
      a[2] = (short)f2bf(f0[2]); a[3] = (short)f2bf(f0[3]);
      a[4] = (short)f2bf(f1[0]); a[5] = (short)f2bf(f1[1]);
      a[6] = (short)f2bf(f1[2]); a[7] = (short)f2bf(f1[3]);
      *(bf16x8*)(Xb + base) = a;
    }
  }
  if (blockIdx.x == 0) {
    int i = threadIdx.x;
    for (int j = i; j < 512; j += 256) {    // fb: [b1|bf1|b2|bf2]
      const float* src = (j < 128) ? b1 : (j < 256) ? bf1 : (j < 384) ? b2 : bf2;
      fb[j] = src[j & 127];
    }
    fgb[i] = (i < 128) ? gam[i] : bet[i & 127];   // [gamma|beta]
  }
}

// ---------- GEMM v3: D[M,128] = act(A[M,K] @ W[K,128] + b) ----------
// Block = 16 rows x 128 cols, 4 waves; wave wv owns cols [wv*32, wv*32+32)
// (2 MFMA tiles). All 4 waves load the same 16 A-rows (L1-shared); B from
// fragment-ordered Wf (coalesced sequential). No LDS, no barriers.
// Grid: M/16 blocks -> 4x the waves of the 64-row layout.
template<int K, bool RELU, bool STATS, int ODT>
__global__ __launch_bounds__(256) void gemm_k(
    const uint16_t* __restrict__ A0, const uint16_t* __restrict__ A1,
    const uint16_t* __restrict__ Wf, const float* __restrict__ bias,
    void* __restrict__ Dv, float* __restrict__ shadow, int M)
{
  constexpr int KT = K / 32;
  const int lane = threadIdx.x & 63;
  const int wv   = threadIdx.x >> 6;
  const int row0 = blockIdx.x * 16;
  if (row0 >= M) return;                    // M % 16 == 0
  const int m = lane & 15, quad = lane >> 4;
  const int arow = row0 + m;

  bf16x8 afr[KT];
#pragma unroll
  for (int kk = 0; kk < KT; kk++) {
    const uint16_t* src = (K == 256 && kk >= 4)
        ? (A1 + (size_t)arow * 128 + (kk - 4) * 32)
        : (A0 + (size_t)arow * 128 + kk * 32);
    afr[kk] = *(const bf16x8*)(src + quad * 8);
  }

#pragma unroll
  for (int t2 = 0; t2 < 2; t2++) {
    const int tt = wv * 2 + t2;
    bf16x8 bfr[KT];
#pragma unroll
    for (int kk = 0; kk < KT; kk++)
      bfr[kk] = *(const bf16x8*)(Wf + ((size_t)(tt * KT + kk) * 64 + lane) * 8);
    f32x4 acc = {0.f, 0.f, 0.f, 0.f};
#pragma unroll
    for (int kk = 0; kk < KT; kk++)
      acc = __builtin_amdgcn_mfma_f32_16x16x32_bf16(afr[kk], bfr[kk], acc, 0, 0, 0);

    const int col = tt * 16 + m;
    const float bv = bias[col];
    float vals[4];
#pragma unroll
    for (int r = 0; r < 4; r++) {
      float v = acc[r] + bv;
      if (RELU) v = fmaxf(v, 0.f);
      vals[r] = v;
      size_t oidx = (size_t)(row0 + quad * 4 + r) * 128 + col;
      if (ODT == 0) ((uint16_t*)Dv)[oidx] = f2bf(v);
      else          ((float*)Dv)[oidx] = v;
    }
    if (STATS) {
      float s = vals[0] + vals[1] + vals[2] + vals[3];
      float q = vals[0]*vals[0] + vals[1]*vals[1] + vals[2]*vals[2] + vals[3]*vals[3];
      s += __shfl_xor(s, 16); s += __shfl_xor(s, 32);   // sum over 16 rows
      q += __shfl_xor(q, 16); q += __shfl_xor(q, 32);
      if (quad == 0) {                      // each col owned by one wave/tile
        float* slot = shadow + (size_t)(blockIdx.x & (NSHADOW - 1)) * 256;
        atomicAdd(&slot[col], s);
        atomicAdd(&slot[128 + col], q);
      }
    }
  }
}

// ---------- gather + max over S neighbors (bf16 rows, 4 rows/wave) ----------
template<int S>
__global__ __launch_bounds__(256) void gather_k(
    const uint32_t* __restrict__ H, const int* __restrict__ idx,
    uint32_t* __restrict__ OUT, int M)
{
  const int lane = threadIdx.x & 63;
  const int gw = blockIdx.x * 4 + (threadIdx.x >> 6);
  const int base = gw * 4;
#pragma unroll
  for (int p = 0; p < 2; p++) {             // 2 passes x 2 interleaved rows
    int ra = base + p * 2, rb = ra + 1;
    if (ra >= M) return;
    bool hasb = rb < M;
    const int* ia = idx + (size_t)ra * S;
    const int* ib = idx + (size_t)(hasb ? rb : ra) * S;
    float a0 = -3.4e38f, a1 = -3.4e38f, b0 = -3.4e38f, b1 = -3.4e38f;
#pragma unroll
    for (int s = 0; s < S; s++) {
      uint32_t ja = (uint32_t)ia[s]; if (ja >= (uint32_t)M) ja = 0;
      uint32_t jb = (uint32_t)ib[s]; if (jb >= (uint32_t)M) jb = 0;
      uint32_t va = H[(size_t)ja * 64 + lane];
      uint32_t vb = H[(size_t)jb * 64 + lane];
      a0 = fmaxf(a0, bflo(va)); a1 = fmaxf(a1, bfhi(va));
      b0 = fmaxf(b0, bflo(vb)); b1 = fmaxf(b1, bfhi(vb));
    }
    OUT[(size_t)ra * 64 + lane] = (__float_as_uint(a1) & 0xffff0000u) | (__float_as_uint(a0) >> 16);
    if (hasb)
      OUT[(size_t)rb * 64 + lane] = (__float_as_uint(b1) & 0xffff0000u) | (__float_as_uint(b0) >> 16);
  }
}

// ---------- BN finalize: shadow slots -> scale/shift[256] (1 block) ----------
__global__ __launch_bounds__(256) void bn_fin_k(
    const float* __restrict__ shadow, const float* __restrict__ fgb,
    float* __restrict__ scsh, int M)
{
  __shared__ float ps[256], pq[256];
  const int tid = threadIdx.x;
  const int col = tid & 127, part = tid >> 7;   // 2 partials x 32 slots
  float s = 0.f, q = 0.f;
#pragma unroll 8
  for (int sl = part * 32; sl < part * 32 + 32; sl++) {
    s += shadow[sl * 256 + col];
    q += shadow[sl * 256 + 128 + col];
  }
  ps[tid] = s; pq[tid] = q;
  __syncthreads();
  if (tid < 128) {
    s = ps[tid] + ps[tid + 128];
    q = pq[tid] + pq[tid + 128];
    float invN = 1.0f / (float)M;
    float mean = s * invN;
    float var  = fmaxf(q * invN - mean * mean, 0.f);
    float g = fgb[tid] * rsqrtf(var + 1e-5f);
    scsh[tid] = g;
    scsh[128 + tid] = fgb[128 + tid] - mean * g;
  }
}

// ---------- BN apply + row L2 normalize (exact-cover, 4 rows/wave) ----------
__global__ __launch_bounds__(256) void bn_norm_k(
    const uint32_t* __restrict__ Y, const float* __restrict__ scsh,
    uint32_t* __restrict__ X, int M)
{
  const int lane = threadIdx.x & 63;
  const int gw = blockIdx.x * 4 + (threadIdx.x >> 6);
  const float s0 = scsh[2*lane],     s1 = scsh[2*lane+1];
  const float h0 = scsh[128+2*lane], h1 = scsh[128+2*lane+1];
  const int base = gw * 4;
#pragma unroll
  for (int p = 0; p < 2; p++) {
    int ra = base + p * 2, rb = ra + 1;
    if (ra >= M) return;
    bool hasb = rb < M;
    uint32_t va = Y[(size_t)ra * 64 + lane];
    uint32_t vb = Y[(size_t)(hasb ? rb : ra) * 64 + lane];
    float a0 = bflo(va) * s0 + h0, a1 = bfhi(va) * s1 + h1;
    float b0 = bflo(vb) * s0 + h0, b1 = bfhi(vb) * s1 + h1;
    float qa = a0*a0 + a1*a1, qb = b0*b0 + b1*b1;
    qa += __shfl_xor(qa, 1);  qb += __shfl_xor(qb, 1);
    qa += __shfl_xor(qa, 2);  qb += __shfl_xor(qb, 2);
    qa += __shfl_xor(qa, 4);  qb += __shfl_xor(qb, 4);
    qa += __shfl_xor(qa, 8);  qb += __shfl_xor(qb, 8);
    qa += __shfl_xor(qa, 16); qb += __shfl_xor(qb, 16);
    qa += __shfl_xor(qa, 32); qb += __shfl_xor(qb, 32);
    float ia = 1.0f / (sqrtf(qa) + 1e-6f);
    float ib = 1.0f / (sqrtf(qb) + 1e-6f);
    a0 *= ia; a1 *= ia; b0 *= ib; b1 *= ib;
    X[(size_t)ra * 64 + lane] = ((uint32_t)f2bf(a1) << 16) | (uint32_t)f2bf(a0);
    if (hasb)
      X[(size_t)rb * 64 + lane] = ((uint32_t)f2bf(b1) << 16) | (uint32_t)f2bf(b0);
  }
}

// ---------- launch ----------
extern "C" void kernel_launch(void* const* d_in, const int* in_sizes, int n_in,
                              void* d_out, int out_size, void* d_ws, size_t ws_size,
                              hipStream_t stream)
{
  const float* features = (const float*)d_in[0];
  const int*   idx1     = (const int*)d_in[1];
  const int*   idx2     = (const int*)d_in[2];
  const float* agg1_W   = (const float*)d_in[3];
  const float* agg1_b   = (const float*)d_in[4];
  const float* fc1_W    = (const float*)d_in[5];
  const float* fc1_b    = (const float*)d_in[6];
  const float* agg2_W   = (const float*)d_in[7];
  const float* agg2_b   = (const float*)d_in[8];
  const float* fc2_W    = (const float*)d_in[9];
  const float* fc2_b    = (const float*)d_in[10];
  const float* bn_g     = (const float*)d_in[11];
  const float* bn_b     = (const float*)d_in[12];

  const int N  = in_sizes[0] / 128;         // 50000 (multiple of 16)
  const int NF = N * 128;

  // workspace carve-up (16B-aligned); ~38.7 MB
  char* w = (char*)d_ws;
  float* shadow = (float*)w; w += NSHADOW * 256 * 4;
  uint16_t* F1  = (uint16_t*)w; w += 128 * 128 * 2;   // fragment-order weights
  uint16_t* Ff1 = (uint16_t*)w; w += 128 * 256 * 2;
  uint16_t* F2  = (uint16_t*)w; w += 128 * 128 * 2;
  uint16_t* Ff2 = (uint16_t*)w; w += 128 * 256 * 2;
  float* fb   = (float*)w; w += 512 * 4;    // [b1|bf1|b2|bf2] f32
  float* fgb  = (float*)w; w += 256 * 4;    // [gamma|beta] f32
  float* scsh = (float*)w; w += 256 * 4;    // BN [scale|shift]
  size_t NB = (size_t)N * 128 * 2;
  uint16_t* Xb   = (uint16_t*)w; w += NB;   // features as bf16
  uint16_t* bufA = (uint16_t*)w; w += NB;   // agg1 -> x
  uint16_t* bufB = (uint16_t*)w; w += NB;   // y -> agg2
  uint16_t* hbuf = (uint16_t*)d_out;        // h1/h2 scratch in d_out (25.6 MB)

  const int pb = (NF / 8 + 255) / 256;      // 3125
  const int tb = (N + 15) / 16;             // 3125: gemm/gather/bn_norm grids

  prep_k<<<pb, 256, 0, stream>>>(features, agg1_W, fc1_W, agg2_W, fc2_W,
      agg1_b, fc1_b, agg2_b, fc2_b, bn_g, bn_b,
      Xb, F1, Ff1, F2, Ff2, fb, fgb, shadow, NF);

  // h1 = relu(Xb @ W1 + b1) -> d_out scratch (bf16)
  gemm_k<128, true, false, 0><<<tb, 256, 0, stream>>>(
      Xb, nullptr, F1, fb + 0, hbuf, nullptr, N);
  // agg1 = max-gather(h1, idx1) -> bufA
  gather_k<25><<<tb, 256, 0, stream>>>((const uint32_t*)hbuf, idx1, (uint32_t*)bufA, N);
  // y = relu([Xb, agg1] @ fc1 + b) -> bufB, fused BN stats
  gemm_k<256, true, true, 0><<<tb, 256, 0, stream>>>(
      Xb, bufA, Ff1, fb + 128, bufB, shadow, N);
  // BN finalize -> scsh
  bn_fin_k<<<1, 256, 0, stream>>>(shadow, fgb, scsh, N);
  // x = L2normalize(BN(y)) -> bufA
  bn_norm_k<<<tb, 256, 0, stream>>>((const uint32_t*)bufB, scsh, (uint32_t*)bufA, N);
  // h2 = relu(x @ W2 + b2) -> d_out scratch
  gemm_k<128, true, false, 0><<<tb, 256, 0, stream>>>(
      bufA, nullptr, F2, fb + 256, hbuf, nullptr, N);
  // agg2 = max-gather(h2, idx2) -> bufB
  gather_k<25><<<tb, 256, 0, stream>>>((const uint32_t*)hbuf, idx2, (uint32_t*)bufB, N);
  // out = [x, agg2] @ fc2 + b -> d_out (f32)
  gemm_k<256, false, false, 1><<<tb, 256, 0, stream>>>(
      bufA, bufB, Ff2, fb + 384, d_out, nullptr, N);

  (void)n_in; (void)out_size; (void)ws_size;
}

// Round 8
// 225.387 us; speedup vs baseline: 1.3380x; 1.1298x over previous
//
#include <hip/hip_runtime.h>
#include <stdint.h>

// ---------- helpers ----------
typedef __attribute__((ext_vector_type(8))) short bf16x8;          // 8 bf16
typedef __attribute__((ext_vector_type(8))) unsigned short u16x8;  // 8 u16
typedef __attribute__((ext_vector_type(4))) float f32x4;

__device__ __forceinline__ float bf2f(uint16_t h) { return __uint_as_float(((uint32_t)h) << 16); }
__device__ __forceinline__ uint16_t f2bf(float f) {  // RNE, finite inputs only
  uint32_t u = __float_as_uint(f);
  u += 0x7fffu + ((u >> 16) & 1u);
  return (uint16_t)(u >> 16);
}

#define NSHADOW 64

// ---------- prep: weights f32 -> bf16 fragment-order; biases/gamma/beta f32;
// zero shadow. Grid: 48 x 256 = 12288 threads.
// Fragment order: chunk c=(tile tt, kstep kk), lane l=(quad q, m):
// 8 elems W[kk*32+q*8+j][tt*16+m] contiguous at D + (c*64+l)*8.
__global__ __launch_bounds__(256) void prep_k(
    const float* __restrict__ W1, const float* __restrict__ Wf1,
    const float* __restrict__ W2, const float* __restrict__ Wf2,
    const float* __restrict__ b1, const float* __restrict__ bf1,
    const float* __restrict__ b2, const float* __restrict__ bf2,
    const float* __restrict__ gam, const float* __restrict__ bet,
    uint16_t* __restrict__ F1, uint16_t* __restrict__ Ff1,
    uint16_t* __restrict__ F2, uint16_t* __restrict__ Ff2,
    float* __restrict__ fb, float* __restrict__ fgb,
    float* __restrict__ shadow)
{
  int t = blockIdx.x * 256 + threadIdx.x;   // 0..12287
  for (int i = t; i < NSHADOW * 256; i += 12288) shadow[i] = 0.f;
  {
    const float* W; uint16_t* D; int KTl; int g;
    if (t < 2048)      { W = W1;  D = F1;  KTl = 4; g = t; }
    else if (t < 6144) { W = Wf1; D = Ff1; KTl = 8; g = t - 2048; }
    else if (t < 8192) { W = W2;  D = F2;  KTl = 4; g = t - 6144; }
    else               { W = Wf2; D = Ff2; KTl = 8; g = t - 8192; }
    int c = g >> 6, l = g & 63;
    int tt = c / KTl, kk = c - tt * KTl;
    int m = l & 15, q = l >> 4;
    int n  = tt * 16 + m;
    int k0 = kk * 32 + q * 8;
    bf16x8 a;
#pragma unroll
    for (int j = 0; j < 8; j++) a[j] = (short)f2bf(W[(size_t)(k0 + j) * 128 + n]);
    *(bf16x8*)(D + (size_t)g * 8) = a;
  }
  if (blockIdx.x == 0) {
    int i = threadIdx.x;
    for (int j = i; j < 512; j += 256) {
      const float* src = (j < 128) ? b1 : (j < 256) ? bf1 : (j < 384) ? b2 : bf2;
      fb[j] = src[j & 127];
    }
    fgb[i] = (i < 128) ? gam[i] : bet[i & 127];
  }
}

// ---------- layer GEMM (K=128): D = relu(A @ W + b), bf16 out ----------
// MODE 1: A = f32 features, convert in-reg, wave0 side-writes bf16 to XOUT.
// MODE 2: A = bf16 y; fused BN (scsh) + row-L2-normalize; wave0 writes x.
// Block = 16 rows x 128 cols, 4 waves (wave owns 2 col-tiles). No LDS.
template<int MODE>
__global__ __launch_bounds__(256) void gemm_l(
    const void* __restrict__ Av, const uint16_t* __restrict__ Wf,
    const float* __restrict__ bias, const float* __restrict__ scsh,
    uint16_t* __restrict__ D, uint16_t* __restrict__ XOUT, int M)
{
  const int lane = threadIdx.x & 63;
  const int wv   = threadIdx.x >> 6;
  const int row0 = blockIdx.x * 16;
  if (row0 >= M) return;                    // M % 16 == 0
  const int m = lane & 15, quad = lane >> 4;
  const int arow = row0 + m;

  bf16x8 afr[4];
  if (MODE == 1) {
    const float* A = (const float*)Av;
#pragma unroll
    for (int kk = 0; kk < 4; kk++) {
      const float* p = A + (size_t)arow * 128 + kk * 32 + quad * 8;
      f32x4 f0 = *(const f32x4*)p;
      f32x4 f1 = *(const f32x4*)(p + 4);
      bf16x8 a;
      a[0] = (short)f2bf(f0[0]); a[1] = (short)f2bf(f0[1]);
      a[2] = (short)f2bf(f0[2]); a[3] = (short)f2bf(f0[3]);
      a[4] = (short)f2bf(f1[0]); a[5] = (short)f2bf(f1[1]);
      a[6] = (short)f2bf(f1[2]); a[7] = (short)f2bf(f1[3]);
      afr[kk] = a;
    }
  } else {
    const uint16_t* A = (const uint16_t*)Av;
    float xv[32];
    float ss = 0.f;
#pragma unroll
    for (int kk = 0; kk < 4; kk++) {
      const int k0 = kk * 32 + quad * 8;
      bf16x8 y8 = *(const bf16x8*)(A + (size_t)arow * 128 + k0);
      f32x4 sc0 = *(const f32x4*)(scsh + k0);
      f32x4 sc1 = *(const f32x4*)(scsh + k0 + 4);
      f32x4 sh0 = *(const f32x4*)(scsh + 128 + k0);
      f32x4 sh1 = *(const f32x4*)(scsh + 128 + k0 + 4);
#pragma unroll
      for (int j = 0; j < 4; j++) {
        float a = bf2f((uint16_t)y8[j])     * sc0[j] + sh0[j];
        float b = bf2f((uint16_t)y8[4 + j]) * sc1[j] + sh1[j];
        xv[kk * 8 + j] = a; xv[kk * 8 + 4 + j] = b;
        ss += a * a + b * b;
      }
    }
    ss += __shfl_xor(ss, 16); ss += __shfl_xor(ss, 32);   // full 128-col row
    float inv = 1.0f / (sqrtf(ss) + 1e-6f);
#pragma unroll
    for (int kk = 0; kk < 4; kk++) {
      bf16x8 a;
#pragma unroll
      for (int j = 0; j < 8; j++) a[j] = (short)f2bf(xv[kk * 8 + j] * inv);
      afr[kk] = a;
    }
  }
  if (wv == 0) {                            // side-write Xb / x
#pragma unroll
    for (int kk = 0; kk < 4; kk++)
      *(bf16x8*)(XOUT + (size_t)arow * 128 + kk * 32 + quad * 8) = afr[kk];
  }

#pragma unroll
  for (int t2 = 0; t2 < 2; t2++) {
    const int tt = wv * 2 + t2;
    bf16x8 bfr[4];
#pragma unroll
    for (int kk = 0; kk < 4; kk++)
      bfr[kk] = *(const bf16x8*)(Wf + ((size_t)(tt * 4 + kk) * 64 + lane) * 8);
    f32x4 acc = {0.f, 0.f, 0.f, 0.f};
#pragma unroll
    for (int kk = 0; kk < 4; kk++)
      acc = __builtin_amdgcn_mfma_f32_16x16x32_bf16(afr[kk], bfr[kk], acc, 0, 0, 0);
    const int col = tt * 16 + m;
    const float bv = bias[col];
#pragma unroll
    for (int r = 0; r < 4; r++) {
      float v = fmaxf(acc[r] + bv, 0.f);
      D[(size_t)(row0 + quad * 4 + r) * 128 + col] = f2bf(v);
    }
  }
}

// ---------- gather-fused GEMM (K=256): D = act([A0, maxgather(H,idx)] @ W + b)
// Stage A: wave gathers 4 rows (dwordx4, u16-max: H is post-ReLU bf16,
// non-negative -> bit-monotone) -> padded LDS tile (16 x 272B rows).
// Stage B: K=256 MFMA GEMM, A1-frags from LDS. STATS also => RELU.
template<bool STATS, int ODT>
__global__ __launch_bounds__(256) void gemm_g(
    const uint16_t* __restrict__ A0, const uint16_t* __restrict__ H,
    const int* __restrict__ idx, const uint16_t* __restrict__ Wf,
    const float* __restrict__ bias, void* __restrict__ Dv,
    float* __restrict__ shadow, int M)
{
  __shared__ __align__(16) uint16_t agg[16 * 136];   // 4352 B, 272B row stride
  const int lane = threadIdx.x & 63;
  const int wv   = threadIdx.x >> 6;
  const int row0 = blockIdx.x * 16;
  if (row0 >= M) return;                    // M % 16 == 0

  {                                         // ---- stage A: gather-max ----
    const int g = lane >> 4, c = lane & 15; // row group / 16B chunk
    const int rw = row0 + wv * 4 + g;
    const int* ir = idx + (size_t)rw * 25;
    u16x8 mx = {0, 0, 0, 0, 0, 0, 0, 0};
#pragma unroll
    for (int s = 0; s < 25; s++) {
      uint32_t j = (uint32_t)ir[s];
      if (j >= (uint32_t)M) j = 0;          // safety clamp
      u16x8 v = *(const u16x8*)(H + (size_t)j * 128 + c * 8);
#pragma unroll
      for (int e = 0; e < 8; e++) mx[e] = (v[e] > mx[e]) ? v[e] : mx[e];
    }
    *(u16x8*)(&agg[(wv * 4 + g) * 136 + c * 8]) = mx;
  }
  __syncthreads();

  const int m = lane & 15, quad = lane >> 4;
  const int arow = row0 + m;
  bf16x8 afr[8];
#pragma unroll
  for (int kk = 0; kk < 4; kk++)
    afr[kk] = *(const bf16x8*)(A0 + (size_t)arow * 128 + kk * 32 + quad * 8);
#pragma unroll
  for (int kk = 0; kk < 4; kk++)
    afr[4 + kk] = *(const bf16x8*)(&agg[m * 136 + kk * 32 + quad * 8]);

#pragma unroll
  for (int t2 = 0; t2 < 2; t2++) {
    const int tt = wv * 2 + t2;
    bf16x8 bfr[8];
#pragma unroll
    for (int kk = 0; kk < 8; kk++)
      bfr[kk] = *(const bf16x8*)(Wf + ((size_t)(tt * 8 + kk) * 64 + lane) * 8);
    f32x4 acc = {0.f, 0.f, 0.f, 0.f};
#pragma unroll
    for (int kk = 0; kk < 8; kk++)
      acc = __builtin_amdgcn_mfma_f32_16x16x32_bf16(afr[kk], bfr[kk], acc, 0, 0, 0);

    const int col = tt * 16 + m;
    const float bv = bias[col];
    float vals[4];
#pragma unroll
    for (int r = 0; r < 4; r++) {
      float v = acc[r] + bv;
      if (STATS) v = fmaxf(v, 0.f);         // fc1 has ReLU; fc2 does not
      vals[r] = v;
      size_t oidx = (size_t)(row0 + quad * 4 + r) * 128 + col;
      if (ODT == 0) ((uint16_t*)Dv)[oidx] = f2bf(v);
      else          ((float*)Dv)[oidx] = v;
    }
    if (STATS) {
      float s = vals[0] + vals[1] + vals[2] + vals[3];
      float q = vals[0]*vals[0] + vals[1]*vals[1] + vals[2]*vals[2] + vals[3]*vals[3];
      s += __shfl_xor(s, 16); s += __shfl_xor(s, 32);
      q += __shfl_xor(q, 16); q += __shfl_xor(q, 32);
      if (quad == 0) {
        float* slot = shadow + (size_t)(blockIdx.x & (NSHADOW - 1)) * 256;
        atomicAdd(&slot[col], s);
        atomicAdd(&slot[128 + col], q);
      }
    }
  }
}

// ---------- BN finalize: shadow slots -> [scale|shift] (1 block) ----------
__global__ __launch_bounds__(256) void bn_fin_k(
    const float* __restrict__ shadow, const float* __restrict__ fgb,
    float* __restrict__ scsh, int M)
{
  __shared__ float ps[256], pq[256];
  const int tid = threadIdx.x;
  const int col = tid & 127, part = tid >> 7;
  float s = 0.f, q = 0.f;
#pragma unroll 8
  for (int sl = part * 32; sl < part * 32 + 32; sl++) {
    s += shadow[sl * 256 + col];
    q += shadow[sl * 256 + 128 + col];
  }
  ps[tid] = s; pq[tid] = q;
  __syncthreads();
  if (tid < 128) {
    s = ps[tid] + ps[tid + 128];
    q = pq[tid] + pq[tid + 128];
    float invN = 1.0f / (float)M;
    float mean = s * invN;
    float var  = fmaxf(q * invN - mean * mean, 0.f);
    float g = fgb[tid] * rsqrtf(var + 1e-5f);
    scsh[tid] = g;
    scsh[128 + tid] = fgb[128 + tid] - mean * g;
  }
}

// ---------- launch ----------
extern "C" void kernel_launch(void* const* d_in, const int* in_sizes, int n_in,
                              void* d_out, int out_size, void* d_ws, size_t ws_size,
                              hipStream_t stream)
{
  const float* features = (const float*)d_in[0];
  const int*   idx1     = (const int*)d_in[1];
  const int*   idx2     = (const int*)d_in[2];
  const float* agg1_W   = (const float*)d_in[3];
  const float* agg1_b   = (const float*)d_in[4];
  const float* fc1_W    = (const float*)d_in[5];
  const float* fc1_b    = (const float*)d_in[6];
  const float* agg2_W   = (const float*)d_in[7];
  const float* agg2_b   = (const float*)d_in[8];
  const float* fc2_W    = (const float*)d_in[9];
  const float* fc2_b    = (const float*)d_in[10];
  const float* bn_g     = (const float*)d_in[11];
  const float* bn_b     = (const float*)d_in[12];

  const int N = in_sizes[0] / 128;          // 50000 (N % 16 == 0)

  // workspace carve-up (16B-aligned); ~64.3 MB
  char* w = (char*)d_ws;
  float* shadow = (float*)w; w += NSHADOW * 256 * 4;
  uint16_t* F1  = (uint16_t*)w; w += 128 * 128 * 2;   // frag-order weights
  uint16_t* Ff1 = (uint16_t*)w; w += 128 * 256 * 2;
  uint16_t* F2  = (uint16_t*)w; w += 128 * 128 * 2;
  uint16_t* Ff2 = (uint16_t*)w; w += 128 * 256 * 2;
  float* fb   = (float*)w; w += 512 * 4;    // [b1|bf1|b2|bf2]
  float* fgb  = (float*)w; w += 256 * 4;    // [gamma|beta]
  float* scsh = (float*)w; w += 256 * 4;    // BN [scale|shift]
  size_t NB = (size_t)N * 128 * 2;
  uint16_t* Xb = (uint16_t*)w; w += NB;     // features bf16
  uint16_t* h1 = (uint16_t*)w; w += NB;
  uint16_t* yb = (uint16_t*)w; w += NB;
  uint16_t* xb = (uint16_t*)w; w += NB;     // normalized layer-1 output
  uint16_t* h2 = (uint16_t*)w; w += NB;

  const int tb = (N + 15) / 16;             // 3125, exact cover

  // 1. weights -> fragment order; biases; zero shadow
  prep_k<<<48, 256, 0, stream>>>(agg1_W, fc1_W, agg2_W, fc2_W,
      agg1_b, fc1_b, agg2_b, fc2_b, bn_g, bn_b,
      F1, Ff1, F2, Ff2, fb, fgb, shadow);
  // 2. h1 = relu(X @ W1 + b1); side-write Xb (bf16 features)
  gemm_l<1><<<tb, 256, 0, stream>>>(features, F1, fb + 0, nullptr, h1, Xb, N);
  // 3. y = relu([Xb, maxgather(h1,idx1)] @ fc1 + b) + BN stats
  gemm_g<true, 0><<<tb, 256, 0, stream>>>(Xb, h1, idx1, Ff1, fb + 128, yb, shadow, N);
  // 4. BN finalize
  bn_fin_k<<<1, 256, 0, stream>>>(shadow, fgb, scsh, N);
  // 5. h2 = relu(L2norm(BN(y)) @ W2 + b2); side-write x
  gemm_l<2><<<tb, 256, 0, stream>>>(yb, F2, fb + 256, scsh, h2, xb, N);
  // 6. out = [x, maxgather(h2,idx2)] @ fc2 + b -> d_out (f32)
  gemm_g<false, 1><<<tb, 256, 0, stream>>>(xb, h2, idx2, Ff2, fb + 384, d_out, nullptr, N);

  (void)n_in; (void)out_size; (void)ws_size;
}

// Round 9
// 223.148 us; speedup vs baseline: 1.3514x; 1.0100x over previous
//
#include <hip/hip_runtime.h>
#include <stdint.h>

// ---------- helpers ----------
typedef __attribute__((ext_vector_type(8))) short bf16x8;          // 8 bf16
typedef __attribute__((ext_vector_type(8))) unsigned short u16x8;  // 8 u16
typedef __attribute__((ext_vector_type(4))) float f32x4;

__device__ __forceinline__ float bf2f(uint16_t h) { return __uint_as_float(((uint32_t)h) << 16); }
__device__ __forceinline__ uint16_t f2bf(float f) {  // RNE, finite inputs only
  uint32_t u = __float_as_uint(f);
  u += 0x7fffu + ((u >> 16) & 1u);
  return (uint16_t)(u >> 16);
}

#define NSHADOW 64

// ---------- prep: weights f32 -> bf16 fragment-order; biases/gamma/beta f32;
// zero shadow. Grid: 48 x 256 = 12288 threads.
// Fragment order: chunk c=(tile tt, kstep kk), lane l=(quad q, m):
// 8 elems W[kk*32+q*8+j][tt*16+m] contiguous at D + (c*64+l)*8.
__global__ __launch_bounds__(256) void prep_k(
    const float* __restrict__ W1, const float* __restrict__ Wf1,
    const float* __restrict__ W2, const float* __restrict__ Wf2,
    const float* __restrict__ b1, const float* __restrict__ bf1,
    const float* __restrict__ b2, const float* __restrict__ bf2,
    const float* __restrict__ gam, const float* __restrict__ bet,
    uint16_t* __restrict__ F1, uint16_t* __restrict__ Ff1,
    uint16_t* __restrict__ F2, uint16_t* __restrict__ Ff2,
    float* __restrict__ fb, float* __restrict__ fgb,
    float* __restrict__ shadow)
{
  int t = blockIdx.x * 256 + threadIdx.x;   // 0..12287
  for (int i = t; i < NSHADOW * 256; i += 12288) shadow[i] = 0.f;
  {
    const float* W; uint16_t* D; int KTl; int g;
    if (t < 2048)      { W = W1;  D = F1;  KTl = 4; g = t; }
    else if (t < 6144) { W = Wf1; D = Ff1; KTl = 8; g = t - 2048; }
    else if (t < 8192) { W = W2;  D = F2;  KTl = 4; g = t - 6144; }
    else               { W = Wf2; D = Ff2; KTl = 8; g = t - 8192; }
    int c = g >> 6, l = g & 63;
    int tt = c / KTl, kk = c - tt * KTl;
    int m = l & 15, q = l >> 4;
    int n  = tt * 16 + m;
    int k0 = kk * 32 + q * 8;
    bf16x8 a;
#pragma unroll
    for (int j = 0; j < 8; j++) a[j] = (short)f2bf(W[(size_t)(k0 + j) * 128 + n]);
    *(bf16x8*)(D + (size_t)g * 8) = a;
  }
  if (blockIdx.x == 0) {
    int i = threadIdx.x;
    for (int j = i; j < 512; j += 256) {
      const float* src = (j < 128) ? b1 : (j < 256) ? bf1 : (j < 384) ? b2 : bf2;
      fb[j] = src[j & 127];
    }
    fgb[i] = (i < 128) ? gam[i] : bet[i & 127];
  }
}

// ---------- layer GEMM (K=128): D = relu(A @ W + b), bf16 out ----------
// MODE 1: A = f32 features, convert in-reg, wave0 side-writes bf16 to XOUT.
// MODE 2: A = bf16 y; fused BN (scsh) + row-L2-normalize; wave0 writes x.
// Block = 16 rows x 128 cols, 4 waves (wave owns 2 col-tiles). No LDS.
template<int MODE>
__global__ __launch_bounds__(256) void gemm_l(
    const void* __restrict__ Av, const uint16_t* __restrict__ Wf,
    const float* __restrict__ bias, const float* __restrict__ scsh,
    uint16_t* __restrict__ D, uint16_t* __restrict__ XOUT, int M)
{
  const int lane = threadIdx.x & 63;
  const int wv   = threadIdx.x >> 6;
  const int row0 = blockIdx.x * 16;
  if (row0 >= M) return;                    // M % 16 == 0
  const int m = lane & 15, quad = lane >> 4;
  const int arow = row0 + m;

  bf16x8 afr[4];
  if (MODE == 1) {
    const float* A = (const float*)Av;
#pragma unroll
    for (int kk = 0; kk < 4; kk++) {
      const float* p = A + (size_t)arow * 128 + kk * 32 + quad * 8;
      f32x4 f0 = *(const f32x4*)p;
      f32x4 f1 = *(const f32x4*)(p + 4);
      bf16x8 a;
      a[0] = (short)f2bf(f0[0]); a[1] = (short)f2bf(f0[1]);
      a[2] = (short)f2bf(f0[2]); a[3] = (short)f2bf(f0[3]);
      a[4] = (short)f2bf(f1[0]); a[5] = (short)f2bf(f1[1]);
      a[6] = (short)f2bf(f1[2]); a[7] = (short)f2bf(f1[3]);
      afr[kk] = a;
    }
  } else {
    const uint16_t* A = (const uint16_t*)Av;
    float xv[32];
    float ss = 0.f;
#pragma unroll
    for (int kk = 0; kk < 4; kk++) {
      const int k0 = kk * 32 + quad * 8;
      bf16x8 y8 = *(const bf16x8*)(A + (size_t)arow * 128 + k0);
      f32x4 sc0 = *(const f32x4*)(scsh + k0);
      f32x4 sc1 = *(const f32x4*)(scsh + k0 + 4);
      f32x4 sh0 = *(const f32x4*)(scsh + 128 + k0);
      f32x4 sh1 = *(const f32x4*)(scsh + 128 + k0 + 4);
#pragma unroll
      for (int j = 0; j < 4; j++) {
        float a = bf2f((uint16_t)y8[j])     * sc0[j] + sh0[j];
        float b = bf2f((uint16_t)y8[4 + j]) * sc1[j] + sh1[j];
        xv[kk * 8 + j] = a; xv[kk * 8 + 4 + j] = b;
        ss += a * a + b * b;
      }
    }
    ss += __shfl_xor(ss, 16); ss += __shfl_xor(ss, 32);   // full 128-col row
    float inv = 1.0f / (sqrtf(ss) + 1e-6f);
#pragma unroll
    for (int kk = 0; kk < 4; kk++) {
      bf16x8 a;
#pragma unroll
      for (int j = 0; j < 8; j++) a[j] = (short)f2bf(xv[kk * 8 + j] * inv);
      afr[kk] = a;
    }
  }
  if (wv == 0) {                            // side-write Xb / x
#pragma unroll
    for (int kk = 0; kk < 4; kk++)
      *(bf16x8*)(XOUT + (size_t)arow * 128 + kk * 32 + quad * 8) = afr[kk];
  }

#pragma unroll
  for (int t2 = 0; t2 < 2; t2++) {
    const int tt = wv * 2 + t2;
    bf16x8 bfr[4];
#pragma unroll
    for (int kk = 0; kk < 4; kk++)
      bfr[kk] = *(const bf16x8*)(Wf + ((size_t)(tt * 4 + kk) * 64 + lane) * 8);
    f32x4 acc = {0.f, 0.f, 0.f, 0.f};
#pragma unroll
    for (int kk = 0; kk < 4; kk++)
      acc = __builtin_amdgcn_mfma_f32_16x16x32_bf16(afr[kk], bfr[kk], acc, 0, 0, 0);
    const int col = tt * 16 + m;
    const float bv = bias[col];
#pragma unroll
    for (int r = 0; r < 4; r++) {
      float v = fmaxf(acc[r] + bv, 0.f);
      D[(size_t)(row0 + quad * 4 + r) * 128 + col] = f2bf(v);
    }
  }
}

// ---------- gather-fused GEMM (K=256): D = act([A0, maxgather(H,idx)] @ W + b)
// Stage A: wave gathers 4 rows; 25 loads batched 8/8/9 into an independent
// v[] buffer -> up to 9 loads in flight (MLP; round-8 profile showed the
// serialized chain capped at ~3.3 TB/s). u16-max is valid: H is post-ReLU
// bf16 (non-negative -> bit-monotone), init 0 exact. Result -> padded LDS.
// Stage B: K=256 MFMA GEMM, A1-frags from LDS. A0-frags prefetched before
// the gather. STATS also => RELU.
template<bool STATS, int ODT>
__global__ __launch_bounds__(256) void gemm_g(
    const uint16_t* __restrict__ A0, const uint16_t* __restrict__ H,
    const int* __restrict__ idx, const uint16_t* __restrict__ Wf,
    const float* __restrict__ bias, void* __restrict__ Dv,
    float* __restrict__ shadow, int M)
{
  __shared__ __align__(16) uint16_t agg[16 * 136];   // 4352 B, 272B row stride
  const int lane = threadIdx.x & 63;
  const int wv   = threadIdx.x >> 6;
  const int row0 = blockIdx.x * 16;
  if (row0 >= M) return;                    // M % 16 == 0
  const int m = lane & 15, quad = lane >> 4;
  const int arow = row0 + m;

  // prefetch A0 fragments (independent of the gather, overlaps it)
  bf16x8 afr[8];
#pragma unroll
  for (int kk = 0; kk < 4; kk++)
    afr[kk] = *(const bf16x8*)(A0 + (size_t)arow * 128 + kk * 32 + quad * 8);

  {                                         // ---- stage A: batched gather-max ----
    // quad = which of the wave's 4 rows; m = 16B chunk within the 256B row
    const int rw = row0 + wv * 4 + quad;
    const int* ir = idx + (size_t)rw * 25;
    u16x8 mx = {0, 0, 0, 0, 0, 0, 0, 0};
#pragma unroll
    for (int b = 0; b < 3; b++) {           // 8 + 8 + 9 = 25
      const int cnt = (b == 2) ? 9 : 8;
      u16x8 v[9];
#pragma unroll
      for (int e = 0; e < 9; e++) {
        if (e < cnt) {
          uint32_t j = (uint32_t)ir[b * 8 + e];
          if (j >= (uint32_t)M) j = 0;      // safety clamp
          v[e] = *(const u16x8*)(H + (size_t)j * 128 + m * 8);
        }
      }
#pragma unroll
      for (int e = 0; e < 9; e++) {
        if (e < cnt) {
#pragma unroll
          for (int x = 0; x < 8; x++) mx[x] = (v[e][x] > mx[x]) ? v[e][x] : mx[x];
        }
      }
    }
    *(u16x8*)(&agg[(wv * 4 + quad) * 136 + m * 8]) = mx;
  }
  __syncthreads();

#pragma unroll
  for (int kk = 0; kk < 4; kk++)
    afr[4 + kk] = *(const bf16x8*)(&agg[m * 136 + kk * 32 + quad * 8]);

#pragma unroll
  for (int t2 = 0; t2 < 2; t2++) {
    const int tt = wv * 2 + t2;
    bf16x8 bfr[8];
#pragma unroll
    for (int kk = 0; kk < 8; kk++)
      bfr[kk] = *(const bf16x8*)(Wf + ((size_t)(tt * 8 + kk) * 64 + lane) * 8);
    f32x4 acc = {0.f, 0.f, 0.f, 0.f};
#pragma unroll
    for (int kk = 0; kk < 8; kk++)
      acc = __builtin_amdgcn_mfma_f32_16x16x32_bf16(afr[kk], bfr[kk], acc, 0, 0, 0);

    const int col = tt * 16 + m;
    const float bv = bias[col];
    float vals[4];
#pragma unroll
    for (int r = 0; r < 4; r++) {
      float v = acc[r] + bv;
      if (STATS) v = fmaxf(v, 0.f);         // fc1 has ReLU; fc2 does not
      vals[r] = v;
      size_t oidx = (size_t)(row0 + quad * 4 + r) * 128 + col;
      if (ODT == 0) ((uint16_t*)Dv)[oidx] = f2bf(v);
      else          ((float*)Dv)[oidx] = v;
    }
    if (STATS) {
      float s = vals[0] + vals[1] + vals[2] + vals[3];
      float q = vals[0]*vals[0] + vals[1]*vals[1] + vals[2]*vals[2] + vals[3]*vals[3];
      s += __shfl_xor(s, 16); s += __shfl_xor(s, 32);
      q += __shfl_xor(q, 16); q += __shfl_xor(q, 32);
      if (quad == 0) {
        float* slot = shadow + (size_t)(blockIdx.x & (NSHADOW - 1)) * 256;
        atomicAdd(&slot[col], s);
        atomicAdd(&slot[128 + col], q);
      }
    }
  }
}

// ---------- BN finalize: shadow slots -> [scale|shift] (1 block) ----------
__global__ __launch_bounds__(256) void bn_fin_k(
    const float* __restrict__ shadow, const float* __restrict__ fgb,
    float* __restrict__ scsh, int M)
{
  __shared__ float ps[256], pq[256];
  const int tid = threadIdx.x;
  const int col = tid & 127, part = tid >> 7;
  float s = 0.f, q = 0.f;
#pragma unroll 8
  for (int sl = part * 32; sl < part * 32 + 32; sl++) {
    s += shadow[sl * 256 + col];
    q += shadow[sl * 256 + 128 + col];
  }
  ps[tid] = s; pq[tid] = q;
  __syncthreads();
  if (tid < 128) {
    s = ps[tid] + ps[tid + 128];
    q = pq[tid] + pq[tid + 128];
    float invN = 1.0f / (float)M;
    float mean = s * invN;
    float var  = fmaxf(q * invN - mean * mean, 0.f);
    float g = fgb[tid] * rsqrtf(var + 1e-5f);
    scsh[tid] = g;
    scsh[128 + tid] = fgb[128 + tid] - mean * g;
  }
}

// ---------- launch ----------
extern "C" void kernel_launch(void* const* d_in, const int* in_sizes, int n_in,
                              void* d_out, int out_size, void* d_ws, size_t ws_size,
                              hipStream_t stream)
{
  const float* features = (const float*)d_in[0];
  const int*   idx1     = (const int*)d_in[1];
  const int*   idx2     = (const int*)d_in[2];
  const float* agg1_W   = (const float*)d_in[3];
  const float* agg1_b   = (const float*)d_in[4];
  const float* fc1_W    = (const float*)d_in[5];
  const float* fc1_b    = (const float*)d_in[6];
  const float* agg2_W   = (const float*)d_in[7];
  const float* agg2_b   = (const float*)d_in[8];
  const float* fc2_W    = (const float*)d_in[9];
  const float* fc2_b    = (const float*)d_in[10];
  const float* bn_g     = (const float*)d_in[11];
  const float* bn_b     = (const float*)d_in[12];

  const int N = in_sizes[0] / 128;          // 50000 (N % 16 == 0)

  // workspace carve-up (16B-aligned); ~64.3 MB
  char* w = (char*)d_ws;
  float* shadow = (float*)w; w += NSHADOW * 256 * 4;
  uint16_t* F1  = (uint16_t*)w; w += 128 * 128 * 2;   // frag-order weights
  uint16_t* Ff1 = (uint16_t*)w; w += 128 * 256 * 2;
  uint16_t* F2  = (uint16_t*)w; w += 128 * 128 * 2;
  uint16_t* Ff2 = (uint16_t*)w; w += 128 * 256 * 2;
  float* fb   = (float*)w; w += 512 * 4;    // [b1|bf1|b2|bf2]
  float* fgb  = (float*)w; w += 256 * 4;    // [gamma|beta]
  float* scsh = (float*)w; w += 256 * 4;    // BN [scale|shift]
  size_t NB = (size_t)N * 128 * 2;
  uint16_t* Xb = (uint16_t*)w; w += NB;     // features bf16
  uint16_t* h1 = (uint16_t*)w; w += NB;
  uint16_t* yb = (uint16_t*)w; w += NB;
  uint16_t* xb = (uint16_t*)w; w += NB;     // normalized layer-1 output
  uint16_t* h2 = (uint16_t*)w; w += NB;

  const int tb = (N + 15) / 16;             // 3125, exact cover

  // 1. weights -> fragment order; biases; zero shadow
  prep_k<<<48, 256, 0, stream>>>(agg1_W, fc1_W, agg2_W, fc2_W,
      agg1_b, fc1_b, agg2_b, fc2_b, bn_g, bn_b,
      F1, Ff1, F2, Ff2, fb, fgb, shadow);
  // 2. h1 = relu(X @ W1 + b1); side-write Xb (bf16 features)
  gemm_l<1><<<tb, 256, 0, stream>>>(features, F1, fb + 0, nullptr, h1, Xb, N);
  // 3. y = relu([Xb, maxgather(h1,idx1)] @ fc1 + b) + BN stats
  gemm_g<true, 0><<<tb, 256, 0, stream>>>(Xb, h1, idx1, Ff1, fb + 128, yb, shadow, N);
  // 4. BN finalize
  bn_fin_k<<<1, 256, 0, stream>>>(shadow, fgb, scsh, N);
  // 5. h2 = relu(L2norm(BN(y)) @ W2 + b2); side-write x
  gemm_l<2><<<tb, 256, 0, stream>>>(yb, F2, fb + 256, scsh, h2, xb, N);
  // 6. out = [x, maxgather(h2,idx2)] @ fc2 + b -> d_out (f32)
  gemm_g<false, 1><<<tb, 256, 0, stream>>>(xb, h2, idx2, Ff2, fb + 384, d_out, nullptr, N);

  (void)n_in; (void)out_size; (void)ws_size;
}